// Round 18
// baseline (1298.837 us; speedup 1.0000x reference)
//
#include <hip/hip_runtime.h>
#include <math.h>

#define BATCH    512
#define T_PAST_  360
#define T_FUT_   1800
#define FUT_SEQ  50
#define WSPF_    34
#define T_TOT    2060
#define T_PAD    2176                 // padded (zero tail) for guard-free prefetch
#define H_SZ     64
#define EPB      16                   // batch elements per block (MFMA N)
#define NGRP     (BATCH / EPB)        // 32 blocks
#define LOG2E    1.44269504f
#define N2LOG2E  (-2.885390082f)

typedef __fp16 f16x8 __attribute__((ext_vector_type(8)));
typedef __fp16 h2v   __attribute__((ext_vector_type(2)));
typedef float  f32x4 __attribute__((ext_vector_type(4)));

__device__ __forceinline__ int   as_i(h2v v)   { return __builtin_bit_cast(int, v); }
__device__ __forceinline__ f16x8 as_f8(int4 v) { return __builtin_bit_cast(f16x8, v); }
__device__ __forceinline__ float rcp_(float x) { return __builtin_amdgcn_rcpf(x); }
__device__ __forceinline__ float exp2_(float x){ return __builtin_amdgcn_exp2f(x); }

__device__ __forceinline__ float dot2_(int a, int b, float c) {
#if __has_builtin(__builtin_amdgcn_fdot2)
    return __builtin_amdgcn_fdot2(__builtin_bit_cast(h2v, a),
                                  __builtin_bit_cast(h2v, b), c, false);
#else
    h2v av = __builtin_bit_cast(h2v, a), bv = __builtin_bit_cast(h2v, b);
    return fmaf((float)av.x, (float)bv.x, fmaf((float)av.y, (float)bv.y, c));
#endif
}

// ---- kernel 1: pack x = [x0,x1][x2,1] fp16 words into d_ws, layout [g][t][n] ----
__global__ __launch_bounds__(256)
void pack_x_kernel(const float* __restrict__ wi, const float* __restrict__ wf,
                   int2* __restrict__ xp) {
    int idx = blockIdx.x * 256 + threadIdx.x;     // = (g*T_PAD + t)*16 + n
    if (idx >= NGRP * T_PAD * EPB) return;
    int n = idx & 15;
    int t = (idx >> 4) % T_PAD;
    int g = idx / (16 * T_PAD);
    int b = g * EPB + n;
    float x0 = 0.f, x1 = 0.f, x2 = 0.f;
    if (t < T_PAST_) {
        const float* p = wi + ((size_t)b * T_PAST_ + t) * 3;
        x0 = p[0]; x1 = p[1]; x2 = p[2];
    } else if (t < T_TOT) {
        const float* p = wf + ((size_t)b * T_FUT_ + (t - T_PAST_)) * 3;
        x0 = p[0]; x1 = p[1]; x2 = p[2];
    }
    int2 v;
    v.x = as_i(__builtin_amdgcn_cvt_pkrtz(x0, x1));
    v.y = as_i(__builtin_amdgcn_cvt_pkrtz(x2, 1.0f));
    xp[idx] = v;
}

// ---- kernel 2: recurrence. 32 blocks x 256 threads (4 waves). ----
// Wave w owns M-tiles tm = 4w+i (i=0..3). k-slot labeling psi(kg,j)=kg*8+j is
// used on BOTH A and B (bijection cancels inside the contraction; verified
// r17). B is stored LINEARLY: B-frag read = hB[buf][frag][lane] (int4),
// conflict-free; writers scatter b16 to hw[kg_u*128 + n*8 + (u&7)], which is
// the exact inverse of that read. C layout (m89-verified): col n = lane&15,
// row = (lane>>4)*4 + reg; A rows are ordered so reg j = gate j of unit
// u = tm*4 + (lane>>4) -> all 4 gates of (u,n) in one lane. x*W_ih + bias
// enters as the MFMA C-init (2 fdot2 per gate, during the B read latency).
__global__ __launch_bounds__(256, 1)
void lstm_mfma_kernel(const float* __restrict__ W_ih, const float* __restrict__ W_hh,
                      const float* __restrict__ b_ih, const float* __restrict__ b_hh,
                      const int2* __restrict__ xp, float* __restrict__ out) {
    __shared__ int4 hB[2][2][64];       // [dbuf][frag(k<32 / k>=32)][lane] = 4 KB

    const int tid  = threadIdx.x;
    const int w    = tid >> 6;          // wave 0..3
    const int lane = tid & 63;
    const int n    = lane & 15;         // elem col (C and B)
    const int q    = lane >> 4;         // C row-quad / B k-group
    const int blk  = blockIdx.x;

    ((int4*)hB)[tid] = make_int4(0, 0, 0, 0);      // h(0) = 0 (256 int4 total)

    // ---- A-frags for 4 tiles: lane holds tile-row tr = lane&15 ----
    // tr = 4*q_a + r -> gate r, unit u = tm*4 + q_a; k-slot = q*8 + j (psi)
    const int q_a = (lane >> 2) & 3;
    const int r   = lane & 3;
    const float s_r = ((r == 2) ? 2.f : 1.f) * LOG2E;
    f16x8 A0[4], A1[4];
    #pragma unroll
    for (int i = 0; i < 4; ++i) {
        const int tm   = 4 * w + i;
        const int arow = r * H_SZ + tm * 4 + q_a;
        #pragma unroll
        for (int j = 0; j < 8; ++j) {
            int k = q * 8 + j;                     // psi(kg=q, j)
            A0[i][j] = (__fp16)(W_hh[(size_t)arow * H_SZ + k]      * s_r);
            A1[i][j] = (__fp16)(W_hh[(size_t)arow * H_SZ + 32 + k] * s_r);
        }
    }

    // ---- C-side: lane owns units u_i = 16w + 4i + q, elem n; packed W_ih ----
    int wih01[4][4], wih2b[4][4];       // [tile i][gate j]
    #pragma unroll
    for (int i = 0; i < 4; ++i) {
        const int u = 16 * w + 4 * i + q;
        #pragma unroll
        for (int j = 0; j < 4; ++j) {
            const float sj = ((j == 2) ? 2.f : 1.f) * LOG2E;
            int rowj = j * H_SZ + u;
            wih01[i][j] = as_i(__builtin_amdgcn_cvt_pkrtz(W_ih[rowj*3+0]*sj,
                                                          W_ih[rowj*3+1]*sj));
            wih2b[i][j] = as_i(__builtin_amdgcn_cvt_pkrtz(W_ih[rowj*3+2]*sj,
                                                          (b_ih[rowj]+b_hh[rowj])*sj));
        }
    }

    const int2* xrow = xp + (size_t)blk * T_PAD * EPB;
    __fp16* outh = (__fp16*)out;        // checkpoint stash (first 128B/token)

    float c0 = 0.f, c1 = 0.f, c2 = 0.f, c3 = 0.f;
    int next_cp = T_PAST_ + WSPF_ - 1;
    int cp_k = 0;
    int2 xw = xrow[0 * EPB + n];

    __syncthreads();

#define TILE(I, CC) {                                                          \
        f32x4 acc;                                                             \
        acc[0] = dot2_(wih2b[I][0], xw.y, dot2_(wih01[I][0], xw.x, 0.f));      \
        acc[1] = dot2_(wih2b[I][1], xw.y, dot2_(wih01[I][1], xw.x, 0.f));      \
        acc[2] = dot2_(wih2b[I][2], xw.y, dot2_(wih01[I][2], xw.x, 0.f));      \
        acc[3] = dot2_(wih2b[I][3], xw.y, dot2_(wih01[I][3], xw.x, 0.f));      \
        acc = __builtin_amdgcn_mfma_f32_16x16x32_f16(A0[I], Bf0, acc, 0, 0, 0);\
        acc = __builtin_amdgcn_mfma_f32_16x16x32_f16(A1[I], Bf1, acc, 0, 0, 0);\
        float gi = rcp_(1.f + exp2_(-acc[0]));                                 \
        float gf = rcp_(1.f + exp2_(-acc[1]));                                 \
        float gg = fmaf(2.f, rcp_(1.f + exp2_(-acc[2])), -1.f);                \
        float go = rcp_(1.f + exp2_(-acc[3]));                                 \
        CC = fmaf(gf, CC, gi * gg);                                            \
        float th = fmaf(2.f, rcp_(1.f + exp2_(CC * N2LOG2E)), -1.f);           \
        float h = go * th;                                                     \
        const int u = 16 * w + 4 * I + q;                                      \
        __fp16* hw = (__fp16*)&hB[DST_][u >> 5][0];                            \
        hw[((u >> 3) & 3) * 128 + n * 8 + (u & 7)] = (__fp16)h;                \
        if (T_ == next_cp)                                                     \
            outh[((size_t)(blk * EPB + n) * FUT_SEQ + cp_k) * 128 + u] = (__fp16)h; \
    }

#define STEP(SRC_, DST_X, T_X) {                                               \
        const int DST_ = (DST_X);                                              \
        const int T_   = (T_X);                                                \
        f16x8 Bf0 = as_f8(hB[SRC_][0][lane]);                                  \
        f16x8 Bf1 = as_f8(hB[SRC_][1][lane]);                                  \
        int2 xn = xrow[(T_ + 1) * EPB + n];          /* prefetch next x */     \
        TILE(0, c0) TILE(1, c1) TILE(2, c2) TILE(3, c3)                        \
        if (T_ == next_cp) { next_cp += WSPF_; ++cp_k; }                       \
        xw = xn;                                                               \
        __syncthreads();                                                       \
    }

    for (int t = 0; t < T_TOT; t += 2) {
        STEP(0, 1, t)
        STEP(1, 0, t + 1)
    }
#undef STEP
#undef TILE
}

// ---- kernel 3: projection. One wave per (b,cp) token; reads fp16 stash
// from out in-wave before overwriting with the f32 projection. ----
__global__ __launch_bounds__(64)
void proj_kernel(const float* __restrict__ W_proj, const float* __restrict__ b_proj,
                 float* __restrict__ out) {
    __shared__ int hs[32];
    const int bcp = blockIdx.x;
    const int j   = threadIdx.x;
    if (j < 32) hs[j] = ((const int*)out)[(size_t)bcp * 64 + j];
    __syncthreads();
    const float* wr = W_proj + j * H_SZ;
    float p = b_proj[j];
    #pragma unroll 8
    for (int m = 0; m < 32; ++m) {
        h2v hv = __builtin_bit_cast(h2v, hs[m]);
        p = fmaf(wr[2*m], (float)hv.x, fmaf(wr[2*m+1], (float)hv.y, p));
    }
    out[(size_t)bcp * 64 + j] = p;
}

extern "C" void kernel_launch(void* const* d_in, const int* in_sizes, int n_in,
                              void* d_out, int out_size, void* d_ws, size_t ws_size,
                              hipStream_t stream) {
    const float* wave_input  = (const float*)d_in[0];
    const float* wave_future = (const float*)d_in[1];
    const float* W_ih        = (const float*)d_in[2];
    const float* W_hh        = (const float*)d_in[3];
    const float* b_ih        = (const float*)d_in[4];
    const float* b_hh        = (const float*)d_in[5];
    const float* W_proj      = (const float*)d_in[6];
    const float* b_proj      = (const float*)d_in[7];
    float* out               = (float*)d_out;

    int2* xp = (int2*)d_ws;             // NGRP*T_PAD*EPB*8 = 8.9 MB

    pack_x_kernel<<<(NGRP * T_PAD * EPB + 255) / 256, 256, 0, stream>>>(
        wave_input, wave_future, xp);
    lstm_mfma_kernel<<<NGRP, 256, 0, stream>>>(
        W_ih, W_hh, b_ih, b_hh, xp, out);
    proj_kernel<<<BATCH * FUT_SEQ, 64, 0, stream>>>(W_proj, b_proj, out);
}

// Round 19
// 952.987 us; speedup vs baseline: 1.3629x; 1.3629x over previous
//
#include <hip/hip_runtime.h>
#include <math.h>

#define BATCH    512
#define T_PAST_  360
#define T_FUT_   1800
#define FUT_SEQ  50
#define WSPF_    34
#define T_TOT    2060
#define T_PAD    2176                 // padded (zero tail) for guard-free prefetch
#define H_SZ     64
#define EPB      16                   // batch elements per block (MFMA N)
#define NGRP     (BATCH / EPB)        // 32 blocks
#define LOG2E    1.44269504f
#define N2LOG2E  (-2.885390082f)

typedef __fp16 f16x8 __attribute__((ext_vector_type(8)));
typedef __fp16 h2v   __attribute__((ext_vector_type(2)));
typedef float  f32x4 __attribute__((ext_vector_type(4)));

__device__ __forceinline__ int   as_i(h2v v)   { return __builtin_bit_cast(int, v); }
__device__ __forceinline__ f16x8 as_f8(int4 v) { return __builtin_bit_cast(f16x8, v); }
__device__ __forceinline__ float rcp_(float x) { return __builtin_amdgcn_rcpf(x); }
__device__ __forceinline__ float exp2_(float x){ return __builtin_amdgcn_exp2f(x); }

__device__ __forceinline__ float dot2_(int a, int b, float c) {
#if __has_builtin(__builtin_amdgcn_fdot2)
    return __builtin_amdgcn_fdot2(__builtin_bit_cast(h2v, a),
                                  __builtin_bit_cast(h2v, b), c, false);
#else
    h2v av = __builtin_bit_cast(h2v, a), bv = __builtin_bit_cast(h2v, b);
    return fmaf((float)av.x, (float)bv.x, fmaf((float)av.y, (float)bv.y, c));
#endif
}

// ---- kernel 1: pack x = [x0,x1][x2,1] fp16 words into d_ws, layout [g][t][n] ----
__global__ __launch_bounds__(256)
void pack_x_kernel(const float* __restrict__ wi, const float* __restrict__ wf,
                   int2* __restrict__ xp) {
    int idx = blockIdx.x * 256 + threadIdx.x;     // = (g*T_PAD + t)*16 + n
    if (idx >= NGRP * T_PAD * EPB) return;
    int n = idx & 15;
    int t = (idx >> 4) % T_PAD;
    int g = idx / (16 * T_PAD);
    int b = g * EPB + n;
    float x0 = 0.f, x1 = 0.f, x2 = 0.f;
    if (t < T_PAST_) {
        const float* p = wi + ((size_t)b * T_PAST_ + t) * 3;
        x0 = p[0]; x1 = p[1]; x2 = p[2];
    } else if (t < T_TOT) {
        const float* p = wf + ((size_t)b * T_FUT_ + (t - T_PAST_)) * 3;
        x0 = p[0]; x1 = p[1]; x2 = p[2];
    }
    int2 v;
    v.x = as_i(__builtin_amdgcn_cvt_pkrtz(x0, x1));
    v.y = as_i(__builtin_amdgcn_cvt_pkrtz(x2, 1.0f));
    xp[idx] = v;
}

// ---- kernel 2: recurrence. 32 blocks x 1024 threads (16 waves). ----
// Synthesis of r17 (16 waves: epilogue/transcendental work spread 4/SIMD) and
// r18 (conflict-free LINEAR hB layout; B-frag read = hB[buf][frag][lane]).
// Wave w owns ONE M-tile tm=w: lane (q=lane>>4, n=lane&15) holds all 4 gates
// of unit u=4w+q, elem n in acc[0..3] (C layout m89-verified; A rows ordered
// gate-major within the tile). k-slot labeling psi(f,q,j)=f*32+q*8+j used on
// BOTH A and B (bijection cancels - verified r17/r18, absmax identical).
// x*W_ih + bias enters as MFMA C-init via packed fdot2 during B-read latency.
__global__ __launch_bounds__(1024, 1)
void lstm_mfma_kernel(const float* __restrict__ W_ih, const float* __restrict__ W_hh,
                      const float* __restrict__ b_ih, const float* __restrict__ b_hh,
                      const int2* __restrict__ xp, float* __restrict__ out) {
    __shared__ int4 hB[2][2][64];       // [dbuf][frag(k<32 / k>=32)][lane] = 4 KB

    const int tid  = threadIdx.x;
    const int w    = tid >> 6;          // wave = M-tile 0..15
    const int lane = tid & 63;
    const int n    = lane & 15;         // elem col (C and B)
    const int q    = lane >> 4;         // C row-quad / B k-group
    const int blk  = blockIdx.x;

    if (tid < 256) ((int4*)hB)[tid] = make_int4(0, 0, 0, 0);   // h(0) = 0

    // ---- A-frags: lane holds tile-row tr = 4*q_a + r -> gate r, unit 4w+q_a ----
    const int q_a = (lane >> 2) & 3;
    const int r   = lane & 3;
    const float s_r = ((r == 2) ? 2.f : 1.f) * LOG2E;          // tanh + exp2 folds
    const int arow = r * H_SZ + 4 * w + q_a;
    f16x8 A0, A1;
    #pragma unroll
    for (int j = 0; j < 8; ++j) {
        int k = q * 8 + j;                                     // psi(f,q,j)
        A0[j] = (__fp16)(W_hh[(size_t)arow * H_SZ + k]      * s_r);
        A1[j] = (__fp16)(W_hh[(size_t)arow * H_SZ + 32 + k] * s_r);
    }

    // ---- C-side: lane owns unit u = 4w + q, elem n; packed W_ih + bias ----
    const int u = 4 * w + q;
    int wih01[4], wih2b[4];
    #pragma unroll
    for (int j = 0; j < 4; ++j) {
        const float sj = ((j == 2) ? 2.f : 1.f) * LOG2E;
        int rowj = j * H_SZ + u;
        wih01[j] = as_i(__builtin_amdgcn_cvt_pkrtz(W_ih[rowj*3+0]*sj,
                                                   W_ih[rowj*3+1]*sj));
        wih2b[j] = as_i(__builtin_amdgcn_cvt_pkrtz(W_ih[rowj*3+2]*sj,
                                                   (b_ih[rowj]+b_hh[rowj])*sj));
    }
    // h write slot: exact inverse of the linear B-frag read (r18-verified)
    __fp16* hw0 = (__fp16*)&hB[0][u >> 5][0];
    __fp16* hw1 = (__fp16*)&hB[1][u >> 5][0];
    const int wslot = ((u >> 3) & 3) * 128 + n * 8 + (u & 7);

    const int2* xrow = xp + (size_t)blk * T_PAD * EPB;
    __fp16* outh = (__fp16*)out;        // checkpoint stash (first 128B/token)

    float c = 0.f;
    int next_cp = T_PAST_ + WSPF_ - 1;
    int cp_k = 0;
    int2 xw = xrow[0 * EPB + n];

    __syncthreads();

#define STEP(SRC_, DST_, T_) {                                                 \
        f16x8 Bf0 = as_f8(hB[SRC_][0][lane]);                                  \
        f16x8 Bf1 = as_f8(hB[SRC_][1][lane]);                                  \
        int2 xn = xrow[(T_ + 1) * EPB + n];            /* prefetch next x */   \
        f32x4 acc;                                                             \
        acc[0] = dot2_(wih2b[0], xw.y, dot2_(wih01[0], xw.x, 0.f));            \
        acc[1] = dot2_(wih2b[1], xw.y, dot2_(wih01[1], xw.x, 0.f));            \
        acc[2] = dot2_(wih2b[2], xw.y, dot2_(wih01[2], xw.x, 0.f));            \
        acc[3] = dot2_(wih2b[3], xw.y, dot2_(wih01[3], xw.x, 0.f));            \
        acc = __builtin_amdgcn_mfma_f32_16x16x32_f16(A0, Bf0, acc, 0, 0, 0);   \
        acc = __builtin_amdgcn_mfma_f32_16x16x32_f16(A1, Bf1, acc, 0, 0, 0);   \
        float gi = rcp_(1.f + exp2_(-acc[0]));                                 \
        float gf = rcp_(1.f + exp2_(-acc[1]));                                 \
        float gg = fmaf(2.f, rcp_(1.f + exp2_(-acc[2])), -1.f);                \
        float go = rcp_(1.f + exp2_(-acc[3]));                                 \
        c = fmaf(gf, c, gi * gg);                                              \
        float th = fmaf(2.f, rcp_(1.f + exp2_(c * N2LOG2E)), -1.f);            \
        float h = go * th;                                                     \
        (DST_ ? hw1 : hw0)[wslot] = (__fp16)h;                                 \
        if (T_ == next_cp) {                                                   \
            outh[((size_t)(blk * EPB + n) * FUT_SEQ + cp_k) * 128 + u] = (__fp16)h; \
            next_cp += WSPF_; ++cp_k;                                          \
        }                                                                      \
        xw = xn;                                                               \
        __syncthreads();                                                       \
    }

    for (int t = 0; t < T_TOT; t += 2) {
        STEP(0, 1, t)
        STEP(1, 0, t + 1)
    }
#undef STEP
}

// ---- kernel 3: projection. One wave per (b,cp) token; reads fp16 stash
// from out in-wave before overwriting with the f32 projection. ----
__global__ __launch_bounds__(64)
void proj_kernel(const float* __restrict__ W_proj, const float* __restrict__ b_proj,
                 float* __restrict__ out) {
    __shared__ int hs[32];
    const int bcp = blockIdx.x;
    const int j   = threadIdx.x;
    if (j < 32) hs[j] = ((const int*)out)[(size_t)bcp * 64 + j];
    __syncthreads();
    const float* wr = W_proj + j * H_SZ;
    float p = b_proj[j];
    #pragma unroll 8
    for (int m = 0; m < 32; ++m) {
        h2v hv = __builtin_bit_cast(h2v, hs[m]);
        p = fmaf(wr[2*m], (float)hv.x, fmaf(wr[2*m+1], (float)hv.y, p));
    }
    out[(size_t)bcp * 64 + j] = p;
}

extern "C" void kernel_launch(void* const* d_in, const int* in_sizes, int n_in,
                              void* d_out, int out_size, void* d_ws, size_t ws_size,
                              hipStream_t stream) {
    const float* wave_input  = (const float*)d_in[0];
    const float* wave_future = (const float*)d_in[1];
    const float* W_ih        = (const float*)d_in[2];
    const float* W_hh        = (const float*)d_in[3];
    const float* b_ih        = (const float*)d_in[4];
    const float* b_hh        = (const float*)d_in[5];
    const float* W_proj      = (const float*)d_in[6];
    const float* b_proj      = (const float*)d_in[7];
    float* out               = (float*)d_out;

    int2* xp = (int2*)d_ws;             // NGRP*T_PAD*EPB*8 = 8.9 MB

    pack_x_kernel<<<(NGRP * T_PAD * EPB + 255) / 256, 256, 0, stream>>>(
        wave_input, wave_future, xp);
    lstm_mfma_kernel<<<NGRP, 1024, 0, stream>>>(
        W_ih, W_hh, b_ih, b_hh, xp, out);
    proj_kernel<<<BATCH * FUT_SEQ, 64, 0, stream>>>(W_proj, b_proj, out);
}

// Round 20
// 840.719 us; speedup vs baseline: 1.5449x; 1.1335x over previous
//
#include <hip/hip_runtime.h>
#include <math.h>

#define BATCH     512
#define T_PAST_   360
#define T_FUT_    1800
#define FUT_SEQ   50
#define WSPF_     34
#define MAX_STEPS (FUT_SEQ * WSPF_)      // 1700
#define T_TOT     (T_PAST_ + MAX_STEPS)  // 2060
#define H_SZ      64
#define LOG2E     1.44269504f
#define N2LOG2E   (-2.885390082f)        // -2/ln2

typedef __fp16 h2 __attribute__((ext_vector_type(2)));

__device__ __forceinline__ h2  as_h2(int v) { return __builtin_bit_cast(h2, v); }
__device__ __forceinline__ int as_i(h2 v)   { return __builtin_bit_cast(int, v); }
__device__ __forceinline__ float rcp_(float x) { return __builtin_amdgcn_rcpf(x); }
__device__ __forceinline__ float exp2_(float x){ return __builtin_amdgcn_exp2f(x); }

// packed-pair dot with f32 accumulate: D = a.x*b.x + a.y*b.y + c
__device__ __forceinline__ float dot2_(int a, int b, float c) {
#if __has_builtin(__builtin_amdgcn_fdot2)
    return __builtin_amdgcn_fdot2(as_h2(a), as_h2(b), c, false);
#else
    h2 av = as_h2(a), bv = as_h2(b);
    return fmaf((float)av.x, (float)bv.x, fmaf((float)av.y, (float)bv.y, c));
#endif
}

// neighbor (lane^1) value via DPP quad_perm [1,0,3,2] — pure VALU
__device__ __forceinline__ float dpp_xor1_(float v) {
    return __builtin_bit_cast(float,
        __builtin_amdgcn_update_dpp(0, __builtin_bit_cast(int, v),
                                    0xB1, 0xF, 0xF, true));
}

// ONE WAVE per batch element, fully self-contained: lane = hidden unit,
// all 4 gate dots in-lane (128 fdot2, 8 independent chains), h exchanged
// through this wave's own LDS buffer with in-wave lgkmcnt ordering ->
// ZERO barriers in the 2060-step loop. This is r8's design with its two
// defects fixed: LDS uniform b128 broadcast instead of 32 readlane->SGPR
// hazards, and a ~200-reg footprint (128 packed-fp16 weight VGPRs, pinned)
// that actually fits (r8 needed ~290 and fell into AGPR/scratch traffic).
// r16's chain eliminations kept: exp2 folds, (x2,1)-packed bias fold,
// DPP pair packing, off-loop projection from packed checkpoint stash.
__global__ __launch_bounds__(64, 1)
void lstm_wave_kernel(const float* __restrict__ wave_input,   // [B, 360, 3]
                      const float* __restrict__ wave_future,  // [B, 1800, 3]
                      const float* __restrict__ W_ih,         // [256, 3]
                      const float* __restrict__ W_hh,         // [256, 64]
                      const float* __restrict__ b_ih,         // [256]
                      const float* __restrict__ b_hh,         // [256]
                      const float* __restrict__ W_proj,       // [64, 64]
                      const float* __restrict__ b_proj,       // [64]
                      float* __restrict__ out)                // [B, 50, 64]
{
    __shared__ __align__(16) int x2_lds[T_TOT * 2];       // packed x, 16.5 KB
    __shared__ __align__(16) int wp_lds[H_SZ * 33];       // packed W_proj, 8.4 KB
    __shared__ __align__(16) int h2_lds[2][H_SZ / 2];     // packed h, 256 B
    __shared__ __align__(16) int stash[FUT_SEQ][H_SZ / 2];// checkpoints, 6.4 KB

    const int b    = blockIdx.x;
    const int lane = threadIdx.x;      // hidden unit index

    // ---- stage x packed fp16: word0=(x0,x1), word1=(x2,1) ----
    {
        const float* wi = wave_input + (size_t)b * (T_PAST_ * 3);
        for (int i = lane; i < T_PAST_; i += 64) {
            x2_lds[2*i  ] = as_i(__builtin_amdgcn_cvt_pkrtz(wi[3*i], wi[3*i+1]));
            x2_lds[2*i+1] = as_i(__builtin_amdgcn_cvt_pkrtz(wi[3*i+2], 1.0f));
        }
        const float* wf = wave_future + (size_t)b * (T_FUT_ * 3);
        for (int i = lane; i < MAX_STEPS; i += 64) {
            int tt = T_PAST_ + i;
            x2_lds[2*tt  ] = as_i(__builtin_amdgcn_cvt_pkrtz(wf[3*i], wf[3*i+1]));
            x2_lds[2*tt+1] = as_i(__builtin_amdgcn_cvt_pkrtz(wf[3*i+2], 1.0f));
        }
    }
    // ---- W_proj rows packed fp16, stride 33 (2-way banks = free) ----
    for (int i = lane; i < H_SZ * 32; i += 64) {
        int j = i >> 5, m = i & 31;
        wp_lds[j * 33 + m] = as_i(__builtin_amdgcn_cvt_pkrtz(
            W_proj[j * H_SZ + 2 * m], W_proj[j * H_SZ + 2 * m + 1]));
    }
    if (lane < 32) h2_lds[0][lane] = 0;        // h(0) = 0

    // ---- all 4 gate rows of W_hh for unit `lane`: 128 packed VGPRs ----
    int w2[4][32];
    #pragma unroll
    for (int g = 0; g < 4; ++g) {
        const float sg = ((g == 2) ? 2.0f : 1.0f) * LOG2E;
        const float* rp = W_hh + (size_t)(g * H_SZ + lane) * H_SZ;
        #pragma unroll
        for (int j = 0; j < 32; ++j)
            w2[g][j] = as_i(__builtin_amdgcn_cvt_pkrtz(rp[2*j]   * sg,
                                                       rp[2*j+1] * sg));
    }
    #pragma unroll
    for (int g = 0; g < 4; ++g)
        #pragma unroll
        for (int k = 0; k < 32; k += 8)
            asm volatile("" : "+v"(w2[g][k+0]), "+v"(w2[g][k+1]),
                              "+v"(w2[g][k+2]), "+v"(w2[g][k+3]),
                              "+v"(w2[g][k+4]), "+v"(w2[g][k+5]),
                              "+v"(w2[g][k+6]), "+v"(w2[g][k+7]));

    // packed W_ih + bias per gate: word0=(Wx0,Wx1), word1=(Wx2, bias)
    int wi01[4], wi2b[4];
    #pragma unroll
    for (int g = 0; g < 4; ++g) {
        const float sg = ((g == 2) ? 2.0f : 1.0f) * LOG2E;
        int row = g * H_SZ + lane;
        wi01[g] = as_i(__builtin_amdgcn_cvt_pkrtz(W_ih[row*3+0]*sg, W_ih[row*3+1]*sg));
        wi2b[g] = as_i(__builtin_amdgcn_cvt_pkrtz(W_ih[row*3+2]*sg,
                                                  (b_ih[row] + b_hh[row])*sg));
    }
    const float bpj = b_proj[lane];

    float c = 0.0f;
    int next_cp = T_PAST_ + WSPF_ - 1;  // 393; all checkpoints odd
    int cp_k = 0;

    __syncthreads();                    // staging visible (single wave, cheap)

#define STEP(SRC, DST, XLO, XHI)                                               \
    {                                                                          \
        const int4* hp = (const int4*)h2_lds[SRC];                             \
        int4 qa[8];                                                            \
        _Pragma("unroll")                                                      \
        for (int i = 0; i < 8; ++i) qa[i] = hp[i];                             \
        const int* qw = (const int*)qa;                                        \
        float acc[4];                                                          \
        _Pragma("unroll")                                                      \
        for (int g = 0; g < 4; ++g) {                                          \
            float aA = dot2_(wi01[g], XLO, 0.0f);                              \
            aA = dot2_(wi2b[g], XHI, aA);                                      \
            float aB = 0.0f;                                                   \
            _Pragma("unroll")                                                  \
            for (int j = 0; j < 16; ++j) {                                     \
                aA = dot2_(w2[g][j],      qw[j],      aA);                     \
                aB = dot2_(w2[g][16 + j], qw[16 + j], aB);                     \
            }                                                                  \
            acc[g] = aA + aB;                                                  \
        }                                                                      \
        float gi = rcp_(1.0f + exp2_(-acc[0]));                                \
        float gf = rcp_(1.0f + exp2_(-acc[1]));                                \
        float gg = fmaf(2.0f, rcp_(1.0f + exp2_(-acc[2])), -1.0f);             \
        float go = rcp_(1.0f + exp2_(-acc[3]));                                \
        c = fmaf(gf, c, gi * gg);                                              \
        float th = fmaf(2.0f, rcp_(1.0f + exp2_(c * N2LOG2E)), -1.0f);         \
        float h = go * th;                                                     \
        float hn = dpp_xor1_(h);                                               \
        pkreg = as_i(__builtin_amdgcn_cvt_pkrtz(h, hn));                       \
        if ((lane & 1) == 0) h2_lds[DST][lane >> 1] = pkreg;                   \
        /* no barrier: own-wave buffer, in-wave lgkmcnt ordering */            \
    }

    int pkreg;
    for (int tb = 0; tb < T_TOT; tb += 2) {
        int4 xq = *(const int4*)&x2_lds[2 * tb];   // x for steps tb, tb+1

        STEP(0, 1, xq.x, xq.y)                     // even step tb

        STEP(1, 0, xq.z, xq.w)                     // odd step tb+1
        if (tb + 1 == next_cp) {                   // checkpoints all odd
            if ((lane & 1) == 0) stash[cp_k][lane >> 1] = pkreg;
            next_cp += WSPF_;
            ++cp_k;
        }
    }
#undef STEP

    // ---- all 3200 projections once, off the recurrent loop ----
    for (int cp = 0; cp < FUT_SEQ; ++cp) {
        float p = bpj;
        #pragma unroll 8
        for (int m = 0; m < 32; ++m)
            p = dot2_(wp_lds[lane * 33 + m], stash[cp][m], p);
        out[((size_t)b * FUT_SEQ + cp) * H_SZ + lane] = p;
    }
}

extern "C" void kernel_launch(void* const* d_in, const int* in_sizes, int n_in,
                              void* d_out, int out_size, void* d_ws, size_t ws_size,
                              hipStream_t stream) {
    const float* wave_input  = (const float*)d_in[0];
    const float* wave_future = (const float*)d_in[1];
    const float* W_ih        = (const float*)d_in[2];
    const float* W_hh        = (const float*)d_in[3];
    const float* b_ih        = (const float*)d_in[4];
    const float* b_hh        = (const float*)d_in[5];
    const float* W_proj      = (const float*)d_in[6];
    const float* b_proj      = (const float*)d_in[7];
    float* out               = (float*)d_out;

    lstm_wave_kernel<<<BATCH, 64, 0, stream>>>(
        wave_input, wave_future, W_ih, W_hh, b_ih, b_hh, W_proj, b_proj, out);
}

// Round 21
// 718.958 us; speedup vs baseline: 1.8066x; 1.1694x over previous
//
#include <hip/hip_runtime.h>
#include <math.h>

#define BATCH     512
#define T_PAST_   360
#define T_FUT_    1800
#define IN_SZ     3
#define H_SZ      64
#define FUT_SEQ   50
#define WSPF_     34
#define MAX_STEPS (FUT_SEQ * WSPF_)      // 1700
#define T_TOT     (T_PAST_ + MAX_STEPS)  // 2060
#define NTHREADS  256
#define LOG2E     1.44269504f
#define N2LOG2E   (-2.885390082f)        // -2/ln2

typedef __fp16 h2 __attribute__((ext_vector_type(2)));

__device__ __forceinline__ h2  as_h2(int v) { return __builtin_bit_cast(h2, v); }
__device__ __forceinline__ int as_i(h2 v)   { return __builtin_bit_cast(int, v); }
__device__ __forceinline__ float rcp_(float x) { return __builtin_amdgcn_rcpf(x); }

__device__ __forceinline__ float exp2_(float x) {
#if __has_builtin(__builtin_amdgcn_exp2f)
    return __builtin_amdgcn_exp2f(x);    // raw v_exp_f32
#else
    return exp2f(x);
#endif
}

// packed-pair dot with f32 accumulate: D = a.x*b.x + a.y*b.y + c
__device__ __forceinline__ float dot2_(int a, int b, float c) {
#if __has_builtin(__builtin_amdgcn_fdot2)
    return __builtin_amdgcn_fdot2(as_h2(a), as_h2(b), c, false);
#else
    h2 av = as_h2(a), bv = as_h2(b);
    return fmaf((float)av.x, (float)bv.x, fmaf((float)av.y, (float)bv.y, c));
#endif
}

// DPP quad_perm (pattern imm): pure VALU cross-lane within each quad
template <int PAT>
__device__ __forceinline__ float quadp_(float v) {
    return __builtin_bit_cast(float,
        __builtin_amdgcn_update_dpp(0, __builtin_bit_cast(int, v),
                                    PAT, 0xF, 0xF, true));
}

// r16 shell (best: 711 us) + ANTI-PHASE STAGGER. The two co-resident blocks
// on each CU (blockIdx c and c+256) run identical periodic step code; if they
// start in phase every wave stalls at the same wall-clock moments and the
// measured per-step time is the SUM of chain+issue (828 cyc) instead of the
// max (~450). One s_sleep(6) (~384 cyc ~ half a step) for the second-dispatch
// block breaks the symmetry permanently (identical per-step timing preserves
// the offset). s_setprio(1) wraps the dependent chain so a wave inside its
// critical section wins arbitration over the other block's off-chain work.
__global__ __launch_bounds__(NTHREADS, 2)
void lstm_fused_kernel(const float* __restrict__ wave_input,   // [B, 360, 3]
                       const float* __restrict__ wave_future,  // [B, 1800, 3]
                       const float* __restrict__ W_ih,         // [256, 3]
                       const float* __restrict__ W_hh,         // [256, 64]
                       const float* __restrict__ b_ih,         // [256]
                       const float* __restrict__ b_hh,         // [256]
                       const float* __restrict__ W_proj,       // [64, 64]
                       const float* __restrict__ b_proj,       // [64]
                       float* __restrict__ out)                // [B, 50, 64]
{
    __shared__ __align__(16) int    x2_lds[T_TOT * 2];        // packed x, 16.5 KB
    __shared__ __align__(16) int    wp_lds[H_SZ * 33];        // packed W_proj, 8.4 KB
    __shared__ __align__(16) __fp16 h2buf[2][H_SZ];           // 256 B
    __shared__ __align__(16) __fp16 stash[FUT_SEQ][H_SZ];     // 6.4 KB

    const int b    = blockIdx.x;
    const int tid  = threadIdx.x;
    const int wv   = tid >> 6;
    const int lane = tid & 63;
    const int g    = lane & 3;          // quad lane: k-slice id (and xb-row id)
    const int u    = wv * 16 + (lane >> 2);   // hidden unit
    const int row  = g * H_SZ + u;      // row whose bias/x this lane folds in

    // ---- stage x sequence packed fp16 (one-time) ----
    {
        const float* wi = wave_input + (size_t)b * (T_PAST_ * IN_SZ);
        for (int i = tid; i < T_PAST_; i += NTHREADS) {
            x2_lds[2*i  ] = as_i(__builtin_amdgcn_cvt_pkrtz(wi[3*i], wi[3*i+1]));
            x2_lds[2*i+1] = as_i(__builtin_amdgcn_cvt_pkrtz(wi[3*i+2], 0.0f));
        }
        const float* wf = wave_future + (size_t)b * (T_FUT_ * IN_SZ);
        for (int i = tid; i < MAX_STEPS; i += NTHREADS) {
            int tt = T_PAST_ + i;
            x2_lds[2*tt  ] = as_i(__builtin_amdgcn_cvt_pkrtz(wf[3*i], wf[3*i+1]));
            x2_lds[2*tt+1] = as_i(__builtin_amdgcn_cvt_pkrtz(wf[3*i+2], 0.0f));
        }
    }
    // ---- W_proj rows packed fp16, stride 33 words (2-way banks = free) ----
    for (int i = tid; i < H_SZ * 32; i += NTHREADS) {
        int j = i >> 5, m = i & 31;
        wp_lds[j * 33 + m] = as_i(__builtin_amdgcn_cvt_pkrtz(
            W_proj[j * H_SZ + 2 * m], W_proj[j * H_SZ + 2 * m + 1]));
    }
    if (tid < H_SZ) h2buf[0][tid] = (__fp16)0.0f;   // h(0) = 0

    // ---- weights: rows {j*64+u, j=0..3}, k-slice [16g,16g+16), gate-j scale ----
    int w2[32];
    #pragma unroll
    for (int j = 0; j < 4; ++j) {
        const float sj = ((j == 2) ? 2.0f : 1.0f) * LOG2E;
        const float* rp = W_hh + (size_t)(j * H_SZ + u) * H_SZ + g * 16;
        #pragma unroll
        for (int q = 0; q < 8; ++q)
            w2[j * 8 + q] = as_i(__builtin_amdgcn_cvt_pkrtz(rp[2*q]   * sj,
                                                            rp[2*q+1] * sj));
    }
    #pragma unroll
    for (int k = 0; k < 32; k += 8)
        asm volatile("" : "+v"(w2[k+0]), "+v"(w2[k+1]), "+v"(w2[k+2]), "+v"(w2[k+3]),
                          "+v"(w2[k+4]), "+v"(w2[k+5]), "+v"(w2[k+6]), "+v"(w2[k+7]));

    // bias + x weights for the lane's own gate row g (pre-reduce fold)
    const float scale = ((g == 2) ? 2.0f : 1.0f) * LOG2E;
    const int wi01 = as_i(__builtin_amdgcn_cvt_pkrtz(W_ih[row*3+0] * scale,
                                                     W_ih[row*3+1] * scale));
    const int wi2p = as_i(__builtin_amdgcn_cvt_pkrtz(W_ih[row*3+2] * scale, 0.0f));
    const float bg = (b_ih[row] + b_hh[row]) * scale;
    // 0/1 masks: lane g injects its xb into partial p_g only
    const float mk0 = (g == 0) ? 1.0f : 0.0f;
    const float mk1 = (g == 1) ? 1.0f : 0.0f;
    const float mk2 = (g == 2) ? 1.0f : 0.0f;
    const float mk3 = (g == 3) ? 1.0f : 0.0f;

    float c = 0.0f;                     // unit u cell state (quad-redundant)
    int next_cp = T_PAST_ + WSPF_ - 1;  // 393; all checkpoints odd
    int cp_k = 0;

    __syncthreads();

    // ---- anti-phase stagger: co-resident pair on a CU is {c, c+256} ----
    if (b & 256) __builtin_amdgcn_s_sleep(6);   // ~384 cyc ~ half a step

#define LSTM_STEP(SRC, DST, XLO, XHI)                                          \
    {                                                                          \
        __builtin_amdgcn_s_setprio(1);                                         \
        const int4* hp4 = (const int4*)&h2buf[SRC][g * 16];                    \
        int4 pv0 = hp4[0], pv1 = hp4[1];                                       \
        float xb = bg;                                                         \
        xb = dot2_(wi01, XLO, xb);                                             \
        xb = dot2_(wi2p, XHI, xb);                                             \
        float p0 = mk0 * xb, p1 = mk1 * xb, p2 = mk2 * xb, p3 = mk3 * xb;      \
        p0 = dot2_(w2[ 0], pv0.x, p0); p1 = dot2_(w2[ 8], pv0.x, p1);          \
        p2 = dot2_(w2[16], pv0.x, p2); p3 = dot2_(w2[24], pv0.x, p3);          \
        p0 = dot2_(w2[ 1], pv0.y, p0); p1 = dot2_(w2[ 9], pv0.y, p1);          \
        p2 = dot2_(w2[17], pv0.y, p2); p3 = dot2_(w2[25], pv0.y, p3);          \
        p0 = dot2_(w2[ 2], pv0.z, p0); p1 = dot2_(w2[10], pv0.z, p1);          \
        p2 = dot2_(w2[18], pv0.z, p2); p3 = dot2_(w2[26], pv0.z, p3);          \
        p0 = dot2_(w2[ 3], pv0.w, p0); p1 = dot2_(w2[11], pv0.w, p1);          \
        p2 = dot2_(w2[19], pv0.w, p2); p3 = dot2_(w2[27], pv0.w, p3);          \
        p0 = dot2_(w2[ 4], pv1.x, p0); p1 = dot2_(w2[12], pv1.x, p1);          \
        p2 = dot2_(w2[20], pv1.x, p2); p3 = dot2_(w2[28], pv1.x, p3);          \
        p0 = dot2_(w2[ 5], pv1.y, p0); p1 = dot2_(w2[13], pv1.y, p1);          \
        p2 = dot2_(w2[21], pv1.y, p2); p3 = dot2_(w2[29], pv1.y, p3);          \
        p0 = dot2_(w2[ 6], pv1.z, p0); p1 = dot2_(w2[14], pv1.z, p1);          \
        p2 = dot2_(w2[22], pv1.z, p2); p3 = dot2_(w2[30], pv1.z, p3);          \
        p0 = dot2_(w2[ 7], pv1.w, p0); p1 = dot2_(w2[15], pv1.w, p1);          \
        p2 = dot2_(w2[23], pv1.w, p2); p3 = dot2_(w2[31], pv1.w, p3);          \
        float e0 = p0 + quadp_<0xB1>(p0);   /* xor1 */                         \
        float e1 = p1 + quadp_<0xB1>(p1);                                      \
        float e2 = p2 + quadp_<0xB1>(p2);                                      \
        float e3 = p3 + quadp_<0xB1>(p3);                                      \
        float f0 = e0 + quadp_<0x4E>(e0);   /* xor2: full sums, every lane */  \
        float f1 = e1 + quadp_<0x4E>(e1);                                      \
        float f2 = e2 + quadp_<0x4E>(e2);                                      \
        float f3 = e3 + quadp_<0x4E>(e3);                                      \
        float gi = rcp_(1.0f + exp2_(-f0));                                    \
        float gf = rcp_(1.0f + exp2_(-f1));                                    \
        float gg = fmaf(2.0f, rcp_(1.0f + exp2_(-f2)), -1.0f);                 \
        float go = rcp_(1.0f + exp2_(-f3));                                    \
        c = fmaf(gf, c, gi * gg);                                              \
        float th = fmaf(2.0f, rcp_(1.0f + exp2_(c * N2LOG2E)), -1.0f);         \
        hreg = go * th;                                                        \
        if (g == 0) h2buf[DST][u] = (__fp16)hreg;                              \
        __builtin_amdgcn_s_setprio(0);                                         \
        __syncthreads();                                                       \
    }

    float hreg;
    for (int tb = 0; tb < T_TOT; tb += 2) {
        int4 xq = *(const int4*)&x2_lds[2 * tb];   // x for steps tb, tb+1

        LSTM_STEP(0, 1, xq.x, xq.y)                // even step tb

        LSTM_STEP(1, 0, xq.z, xq.w)                // odd step tb+1
        if (tb + 1 == next_cp) {                   // checkpoints are all odd
            if (g == 0) stash[cp_k][u] = (__fp16)hreg;
            next_cp += WSPF_;
            ++cp_k;
        }
    }
#undef LSTM_STEP

    // ---- all 3200 projections once, off the recurrent loop ----
    for (int idx = tid; idx < FUT_SEQ * H_SZ; idx += NTHREADS) {
        int k = idx >> 6, j = idx & 63;
        const int* hs = (const int*)&stash[k][0];   // 32 packed pairs
        float p = b_proj[j];
        #pragma unroll 8
        for (int m = 0; m < 32; ++m)
            p = dot2_(wp_lds[j * 33 + m], hs[m], p);
        out[((size_t)b * FUT_SEQ + k) * H_SZ + j] = p;
    }
}

extern "C" void kernel_launch(void* const* d_in, const int* in_sizes, int n_in,
                              void* d_out, int out_size, void* d_ws, size_t ws_size,
                              hipStream_t stream) {
    const float* wave_input  = (const float*)d_in[0];
    const float* wave_future = (const float*)d_in[1];
    const float* W_ih        = (const float*)d_in[2];
    const float* W_hh        = (const float*)d_in[3];
    const float* b_ih        = (const float*)d_in[4];
    const float* b_hh        = (const float*)d_in[5];
    const float* W_proj      = (const float*)d_in[6];
    const float* b_proj      = (const float*)d_in[7];
    float* out               = (float*)d_out;

    lstm_fused_kernel<<<BATCH, NTHREADS, 0, stream>>>(
        wave_input, wave_future, W_ih, W_hh, b_ih, b_hh, W_proj, b_proj, out);
}